// Round 1
// baseline (15.194 us; speedup 1.0000x reference)
//
#include <hip/hip_runtime.h>
#include <hip/hip_bf16.h>

// Sparse pattern: 5 diagonal entries + (0,4) and (4,0) corners.
// X_full = I + scatter(X); out = sum((solve(X_full, A) - I)^2).
// Tiny fixed-size problem (5x5) -> single-thread serial solve; the whole
// kernel is launch-latency-bound.

__global__ void Invert_36129264894624_kernel(const float* __restrict__ X,
                                             const float* __restrict__ A,
                                             float* __restrict__ out) {
    if (threadIdx.x != 0 || blockIdx.x != 0) return;

    const int rows[7] = {0, 1, 2, 3, 4, 0, 4};
    const int cols[7] = {0, 1, 2, 3, 4, 4, 0};

    // M = I + scatter(X)
    double M[5][5];
    #pragma unroll
    for (int i = 0; i < 5; ++i)
        #pragma unroll
        for (int j = 0; j < 5; ++j)
            M[i][j] = (i == j) ? 1.0 : 0.0;
    #pragma unroll
    for (int k = 0; k < 7; ++k)
        M[rows[k]][cols[k]] += (double)X[k];

    // B = A (RHS, will become the solution via Gauss-Jordan)
    double B[5][5];
    #pragma unroll
    for (int i = 0; i < 5; ++i)
        #pragma unroll
        for (int j = 0; j < 5; ++j)
            B[i][j] = (double)A[i * 5 + j];

    // Gauss-Jordan with partial pivoting.
    for (int c = 0; c < 5; ++c) {
        // pivot search
        int p = c;
        double best = fabs(M[c][c]);
        for (int r = c + 1; r < 5; ++r) {
            double v = fabs(M[r][c]);
            if (v > best) { best = v; p = r; }
        }
        if (p != c) {
            for (int j = 0; j < 5; ++j) {
                double t = M[c][j]; M[c][j] = M[p][j]; M[p][j] = t;
                t = B[c][j]; B[c][j] = B[p][j]; B[p][j] = t;
            }
        }
        double inv = 1.0 / M[c][c];
        for (int j = 0; j < 5; ++j) { M[c][j] *= inv; B[c][j] *= inv; }
        for (int r = 0; r < 5; ++r) {
            if (r == c) continue;
            double f = M[r][c];
            if (f != 0.0) {
                for (int j = 0; j < 5; ++j) {
                    M[r][j] -= f * M[c][j];
                    B[r][j] -= f * B[c][j];
                }
            }
        }
    }

    // sum((B - I)^2)
    double s = 0.0;
    #pragma unroll
    for (int i = 0; i < 5; ++i)
        #pragma unroll
        for (int j = 0; j < 5; ++j) {
            double d = B[i][j] - ((i == j) ? 1.0 : 0.0);
            s += d * d;
        }

    out[0] = (float)s;
}

extern "C" void kernel_launch(void* const* d_in, const int* in_sizes, int n_in,
                              void* d_out, int out_size, void* d_ws, size_t ws_size,
                              hipStream_t stream) {
    const float* X = (const float*)d_in[0];  // 7 values
    const float* A = (const float*)d_in[1];  // 5x5
    float* out = (float*)d_out;              // scalar
    Invert_36129264894624_kernel<<<1, 64, 0, stream>>>(X, A, out);
}

// Round 2
// 11.291 us; speedup vs baseline: 1.3456x; 1.3456x over previous
//
#include <hip/hip_runtime.h>
#include <hip/hip_bf16.h>

// Sparse pattern: 5 diagonal entries + (0,4) and (4,0) corners.
// X_full = I + scatter(X); out = sum((solve(X_full, A) - I)^2).
// Tiny fixed-size 5x5 problem -> single-lane serial Gauss-Jordan in f32.
// Launch-latency-bound; f32 shortens the serial dependent chain vs f64.

__global__ void Invert_36129264894624_kernel(const float* __restrict__ X,
                                             const float* __restrict__ A,
                                             float* __restrict__ out) {
    if (threadIdx.x != 0 || blockIdx.x != 0) return;

    const int rows[7] = {0, 1, 2, 3, 4, 0, 4};
    const int cols[7] = {0, 1, 2, 3, 4, 4, 0};

    // M = I + scatter(X)
    float M[5][5];
    #pragma unroll
    for (int i = 0; i < 5; ++i)
        #pragma unroll
        for (int j = 0; j < 5; ++j)
            M[i][j] = (i == j) ? 1.0f : 0.0f;
    #pragma unroll
    for (int k = 0; k < 7; ++k)
        M[rows[k]][cols[k]] += X[k];

    // B = A (RHS, becomes the solution via Gauss-Jordan)
    float B[5][5];
    #pragma unroll
    for (int i = 0; i < 5; ++i)
        #pragma unroll
        for (int j = 0; j < 5; ++j)
            B[i][j] = A[i * 5 + j];

    // Gauss-Jordan with partial pivoting (f32).
    for (int c = 0; c < 5; ++c) {
        int p = c;
        float best = fabsf(M[c][c]);
        for (int r = c + 1; r < 5; ++r) {
            float v = fabsf(M[r][c]);
            if (v > best) { best = v; p = r; }
        }
        if (p != c) {
            for (int j = 0; j < 5; ++j) {
                float t = M[c][j]; M[c][j] = M[p][j]; M[p][j] = t;
                t = B[c][j]; B[c][j] = B[p][j]; B[p][j] = t;
            }
        }
        float inv = 1.0f / M[c][c];
        for (int j = 0; j < 5; ++j) { M[c][j] *= inv; B[c][j] *= inv; }
        for (int r = 0; r < 5; ++r) {
            if (r == c) continue;
            float f = M[r][c];
            for (int j = 0; j < 5; ++j) {
                M[r][j] = __builtin_fmaf(-f, M[c][j], M[r][j]);
                B[r][j] = __builtin_fmaf(-f, B[c][j], B[r][j]);
            }
        }
    }

    // sum((B - I)^2)
    float s = 0.0f;
    #pragma unroll
    for (int i = 0; i < 5; ++i)
        #pragma unroll
        for (int j = 0; j < 5; ++j) {
            float d = B[i][j] - ((i == j) ? 1.0f : 0.0f);
            s += d * d;
        }

    out[0] = s;
}

extern "C" void kernel_launch(void* const* d_in, const int* in_sizes, int n_in,
                              void* d_out, int out_size, void* d_ws, size_t ws_size,
                              hipStream_t stream) {
    const float* X = (const float*)d_in[0];  // 7 values
    const float* A = (const float*)d_in[1];  // 5x5
    float* out = (float*)d_out;              // scalar
    Invert_36129264894624_kernel<<<1, 64, 0, stream>>>(X, A, out);
}

// Round 3
// 9.808 us; speedup vs baseline: 1.5491x; 1.1512x over previous
//
#include <hip/hip_runtime.h>
#include <hip/hip_bf16.h>

// Sparse pattern: 5 diagonal entries + (0,4) and (4,0) corners -> ARROW matrix:
//   M = diag(d0..d4), M[0][4]=a, M[4][0]=b, where d_i = 1 + X[i], a=X[5], b=X[6].
// Closed-form solve:
//   rows 1..3:  Y[i][j] = A[i][j] / d_i
//   rows 0,4 :  2x2 system [d0 a; b d4], det = d0*d4 - a*b
//     Y[0][j] = (d4*A[0][j] - a*A[4][j]) / det
//     Y[4][j] = (d0*A[4][j] - b*A[0][j]) / det
// out = sum((Y - I)^2).  Launch-latency-bound; body is ~40 FMAs + 4 rcp.

__global__ void Invert_36129264894624_kernel(const float* __restrict__ X,
                                             const float* __restrict__ A,
                                             float* __restrict__ out) {
    if (threadIdx.x != 0 || blockIdx.x != 0) return;

    const float d0 = 1.0f + X[0];
    const float d1 = 1.0f + X[1];
    const float d2 = 1.0f + X[2];
    const float d3 = 1.0f + X[3];
    const float d4 = 1.0f + X[4];
    const float a  = X[5];   // (0,4)
    const float b  = X[6];   // (4,0)

    const float det  = __builtin_fmaf(d0, d4, -a * b);
    const float rdet = __builtin_amdgcn_rcpf(det);
    const float r1   = __builtin_amdgcn_rcpf(d1);
    const float r2   = __builtin_amdgcn_rcpf(d2);
    const float r3   = __builtin_amdgcn_rcpf(d3);

    float s = 0.0f;
    #pragma unroll
    for (int j = 0; j < 5; ++j) {
        const float a0 = A[0 * 5 + j];
        const float a1 = A[1 * 5 + j];
        const float a2 = A[2 * 5 + j];
        const float a3 = A[3 * 5 + j];
        const float a4 = A[4 * 5 + j];

        const float y0 = (__builtin_fmaf(d4, a0, -a * a4)) * rdet;
        const float y1 = a1 * r1;
        const float y2 = a2 * r2;
        const float y3 = a3 * r3;
        const float y4 = (__builtin_fmaf(d0, a4, -b * a0)) * rdet;

        const float e0 = y0 - (j == 0 ? 1.0f : 0.0f);
        const float e1 = y1 - (j == 1 ? 1.0f : 0.0f);
        const float e2 = y2 - (j == 2 ? 1.0f : 0.0f);
        const float e3 = y3 - (j == 3 ? 1.0f : 0.0f);
        const float e4 = y4 - (j == 4 ? 1.0f : 0.0f);

        s = __builtin_fmaf(e0, e0, s);
        s = __builtin_fmaf(e1, e1, s);
        s = __builtin_fmaf(e2, e2, s);
        s = __builtin_fmaf(e3, e3, s);
        s = __builtin_fmaf(e4, e4, s);
    }

    out[0] = s;
}

extern "C" void kernel_launch(void* const* d_in, const int* in_sizes, int n_in,
                              void* d_out, int out_size, void* d_ws, size_t ws_size,
                              hipStream_t stream) {
    const float* X = (const float*)d_in[0];  // 7 values
    const float* A = (const float*)d_in[1];  // 5x5
    float* out = (float*)d_out;              // scalar
    Invert_36129264894624_kernel<<<1, 64, 0, stream>>>(X, A, out);
}

// Round 4
// 9.673 us; speedup vs baseline: 1.5708x; 1.0140x over previous
//
#include <hip/hip_runtime.h>
#include <hip/hip_bf16.h>

// ARROW matrix closed-form solve (see R2). Final micro-opt round:
// - vectorized input loads (float4), - no entry branch (all lanes compute
//   redundantly, store predicated to lane 0), - rcp for all divides.
// Launch-latency-bound: ~9.8us measured vs ~0.3us of body.

__global__ void __launch_bounds__(64, 1)
Invert_36129264894624_kernel(const float* __restrict__ X,
                             const float* __restrict__ A,
                             float* __restrict__ out) {
    // X: 7 floats = float4 + float2 + float (in-bounds of 28B)
    const float4 x03 = *reinterpret_cast<const float4*>(X);
    const float2 x45 = *reinterpret_cast<const float2*>(X + 4);
    const float  x6  = X[6];

    // A: 25 floats = 6x float4 + 1 scalar
    const float4 q0 = *reinterpret_cast<const float4*>(A +  0);
    const float4 q1 = *reinterpret_cast<const float4*>(A +  4);
    const float4 q2 = *reinterpret_cast<const float4*>(A +  8);
    const float4 q3 = *reinterpret_cast<const float4*>(A + 12);
    const float4 q4 = *reinterpret_cast<const float4*>(A + 16);
    const float4 q5 = *reinterpret_cast<const float4*>(A + 20);
    const float  a24 = A[24];

    const float d0 = 1.0f + x03.x;
    const float d1 = 1.0f + x03.y;
    const float d2 = 1.0f + x03.z;
    const float d3 = 1.0f + x03.w;
    const float d4 = 1.0f + x45.x;
    const float a  = x45.y;  // (0,4)
    const float b  = x6;     // (4,0)

    const float det  = __builtin_fmaf(d0, d4, -a * b);
    const float rdet = __builtin_amdgcn_rcpf(det);
    const float r1   = __builtin_amdgcn_rcpf(d1);
    const float r2   = __builtin_amdgcn_rcpf(d2);
    const float r3   = __builtin_amdgcn_rcpf(d3);

    // Row views of A (row i, cols 0..4)
    const float A0[5] = {q0.x, q0.y, q0.z, q0.w, q1.x};
    const float A1[5] = {q1.y, q1.z, q1.w, q2.x, q2.y};
    const float A2[5] = {q2.z, q2.w, q3.x, q3.y, q3.z};
    const float A3[5] = {q3.w, q4.x, q4.y, q4.z, q4.w};
    const float A4[5] = {q5.x, q5.y, q5.z, q5.w, a24};

    float s = 0.0f;
    #pragma unroll
    for (int j = 0; j < 5; ++j) {
        const float y0 = __builtin_fmaf(d4, A0[j], -a * A4[j]) * rdet;
        const float y1 = A1[j] * r1;
        const float y2 = A2[j] * r2;
        const float y3 = A3[j] * r3;
        const float y4 = __builtin_fmaf(d0, A4[j], -b * A0[j]) * rdet;

        const float e0 = y0 - (j == 0 ? 1.0f : 0.0f);
        const float e1 = y1 - (j == 1 ? 1.0f : 0.0f);
        const float e2 = y2 - (j == 2 ? 1.0f : 0.0f);
        const float e3 = y3 - (j == 3 ? 1.0f : 0.0f);
        const float e4 = y4 - (j == 4 ? 1.0f : 0.0f);

        s = __builtin_fmaf(e0, e0, s);
        s = __builtin_fmaf(e1, e1, s);
        s = __builtin_fmaf(e2, e2, s);
        s = __builtin_fmaf(e3, e3, s);
        s = __builtin_fmaf(e4, e4, s);
    }

    if (threadIdx.x == 0) out[0] = s;
}

extern "C" void kernel_launch(void* const* d_in, const int* in_sizes, int n_in,
                              void* d_out, int out_size, void* d_ws, size_t ws_size,
                              hipStream_t stream) {
    const float* X = (const float*)d_in[0];  // 7 values
    const float* A = (const float*)d_in[1];  // 5x5
    float* out = (float*)d_out;              // scalar
    Invert_36129264894624_kernel<<<1, 64, 0, stream>>>(X, A, out);
}